// Round 7
// baseline (246.868 us; speedup 1.0000x reference)
//
#include <hip/hip_runtime.h>

constexpr int BLK = 256;   // threads per block
constexpr int EPT = 2;     // elements per thread
constexpr int TILE = BLK * EPT;  // 512 elements per block

__device__ __forceinline__ void nerf_compute(
    float r, float th, float ph,
    float Ax, float Ay, float Az,
    float Bx, float By, float Bz,
    float Cx, float Cy, float Cz,
    float& Dx, float& Dy, float& Dz)
{
    float sth, cth, sph, cph;
    __sincosf(th, &sth, &cth);
    __sincosf(ph, &sph, &cph);
    float d0 = r * cth;
    float d1 = r * cph * sth;
    float d2 = r * sph * sth;

    float v1x = Bx - Ax, v1y = By - Ay, v1z = Bz - Az;
    float v2x = Cx - Bx, v2y = Cy - By, v2z = Cz - Bz;

    float inv2 = rsqrtf(v2x * v2x + v2y * v2y + v2z * v2z);
    float bcx = v2x * inv2, bcy = v2y * inv2, bcz = v2z * inv2;

    // n = normalize(cross(vec1, bc))
    float nx = v1y * bcz - v1z * bcy;
    float ny = v1z * bcx - v1x * bcz;
    float nz = v1x * bcy - v1y * bcx;
    float invn = rsqrtf(nx * nx + ny * ny + nz * nz);
    nx *= invn; ny *= invn; nz *= invn;

    // m = cross(n, bc)
    float mx = ny * bcz - nz * bcy;
    float my = nz * bcx - nx * bcz;
    float mz = nx * bcy - ny * bcx;

    Dx = d0 * bcx + d1 * mx + d2 * nx + Cx;
    Dy = d0 * bcy + d1 * my + d2 * ny + Cy;
    Dz = d0 * bcz + d1 * mz + d2 * nz + Cz;
}

__global__ __launch_bounds__(BLK) void nerf_kernel(
    const float* __restrict__ mc, const float* __restrict__ ic,
    float* __restrict__ out, int N)
{
    __shared__ float s_mc[TILE * 9];   // 18432 B
    __shared__ float s_ic[TILE * 3];   //  6144 B
    __shared__ float s_out[TILE * 3];  //  6144 B  -> 30.7 KB total, 5 blocks/CU by LDS

    const int t = threadIdx.x;
    const int base = blockIdx.x * TILE;          // max 4e6, fits int
    const int rem = N - base;

    if (rem >= TILE) {
        // ---- fast path: full 512-elem tile, cooperative float4 staging ----
        const float4* mc4 = reinterpret_cast<const float4*>(mc + (size_t)base * 9);
        const float4* ic4 = reinterpret_cast<const float4*>(ic + (size_t)base * 3);
        float4* s_mc4 = reinterpret_cast<float4*>(s_mc);
        float4* s_ic4 = reinterpret_cast<float4*>(s_ic);

        // 1152 float4 of mainchain (4.5 per thread)
        #pragma unroll
        for (int j = 0; j < 4; ++j)
            s_mc4[t + j * BLK] = mc4[t + j * BLK];
        if (t < TILE * 9 / 4 - 4 * BLK)          // remaining 128
            s_mc4[t + 4 * BLK] = mc4[t + 4 * BLK];
        // 384 float4 of inner (1.5 per thread)
        s_ic4[t] = ic4[t];
        if (t < TILE * 3 / 4 - BLK)              // remaining 128
            s_ic4[t + BLK] = ic4[t + BLK];

        __syncthreads();

        #pragma unroll
        for (int e = 0; e < EPT; ++e) {
            const int elem = t + e * BLK;
            float r  = s_ic[elem * 3 + 0];
            float th = s_ic[elem * 3 + 1];
            float ph = s_ic[elem * 3 + 2];

            const float* p = &s_mc[elem * 9];
            float Dx, Dy, Dz;
            nerf_compute(r, th, ph,
                         p[0], p[1], p[2],
                         p[3], p[4], p[5],
                         p[6], p[7], p[8],
                         Dx, Dy, Dz);

            s_out[elem * 3 + 0] = Dx;
            s_out[elem * 3 + 1] = Dy;
            s_out[elem * 3 + 2] = Dz;
        }

        __syncthreads();

        // 384 float4 out
        float4* o4 = reinterpret_cast<float4*>(out + (size_t)base * 3);
        const float4* s_out4 = reinterpret_cast<const float4*>(s_out);
        o4[t] = s_out4[t];
        if (t < TILE * 3 / 4 - BLK)
            o4[t + BLK] = s_out4[t + BLK];
    } else {
        // ---- tail path (last block: rem = 256 for N = 4M) ----
        #pragma unroll
        for (int e = 0; e < EPT; ++e) {
            const int i = base + t + e * BLK;
            if (i < N) {
                const float* p = mc + (size_t)i * 9;
                float r  = ic[(size_t)i * 3 + 0];
                float th = ic[(size_t)i * 3 + 1];
                float ph = ic[(size_t)i * 3 + 2];
                float Dx, Dy, Dz;
                nerf_compute(r, th, ph,
                             p[0], p[1], p[2],
                             p[3], p[4], p[5],
                             p[6], p[7], p[8],
                             Dx, Dy, Dz);
                out[(size_t)i * 3 + 0] = Dx;
                out[(size_t)i * 3 + 1] = Dy;
                out[(size_t)i * 3 + 2] = Dz;
            }
        }
    }
}

extern "C" void kernel_launch(void* const* d_in, const int* in_sizes, int n_in,
                              void* d_out, int out_size, void* d_ws, size_t ws_size,
                              hipStream_t stream) {
    const float* mc = (const float*)d_in[0];   // (3N, 3) float32
    const float* ic = (const float*)d_in[1];   // (N, 3)  float32
    float* out = (float*)d_out;                // (N, 3)  float32

    const int N = in_sizes[1] / 3;
    const int grid = (N + TILE - 1) / TILE;
    nerf_kernel<<<grid, BLK, 0, stream>>>(mc, ic, out, N);
}

// Round 10
// 230.376 us; speedup vs baseline: 1.0716x; 1.0716x over previous
//
#include <hip/hip_runtime.h>

constexpr int BLK = 256;   // threads per block
constexpr int EPT = 2;     // elements per thread
constexpr int TILE = BLK * EPT;  // 512 elements per block

// native 16B vector type — __builtin_nontemporal_* rejects HIP_vector_type
using f4 = __attribute__((ext_vector_type(4))) float;

__device__ __forceinline__ void nerf_compute(
    float r, float th, float ph,
    float Ax, float Ay, float Az,
    float Bx, float By, float Bz,
    float Cx, float Cy, float Cz,
    float& Dx, float& Dy, float& Dz)
{
    float sth, cth, sph, cph;
    __sincosf(th, &sth, &cth);
    __sincosf(ph, &sph, &cph);
    float d0 = r * cth;
    float d1 = r * cph * sth;
    float d2 = r * sph * sth;

    float v1x = Bx - Ax, v1y = By - Ay, v1z = Bz - Az;
    float v2x = Cx - Bx, v2y = Cy - By, v2z = Cz - Bz;

    float inv2 = rsqrtf(v2x * v2x + v2y * v2y + v2z * v2z);
    float bcx = v2x * inv2, bcy = v2y * inv2, bcz = v2z * inv2;

    // n = normalize(cross(vec1, bc))
    float nx = v1y * bcz - v1z * bcy;
    float ny = v1z * bcx - v1x * bcz;
    float nz = v1x * bcy - v1y * bcx;
    float invn = rsqrtf(nx * nx + ny * ny + nz * nz);
    nx *= invn; ny *= invn; nz *= invn;

    // m = cross(n, bc)
    float mx = ny * bcz - nz * bcy;
    float my = nz * bcx - nx * bcz;
    float mz = nx * bcy - ny * bcx;

    Dx = d0 * bcx + d1 * mx + d2 * nx + Cx;
    Dy = d0 * bcy + d1 * my + d2 * ny + Cy;
    Dz = d0 * bcz + d1 * mz + d2 * nz + Cz;
}

__global__ __launch_bounds__(BLK) void nerf_kernel(
    const float* __restrict__ mc, const float* __restrict__ ic,
    float* __restrict__ out, int N)
{
    __shared__ float s_mc[TILE * 9];   // 18432 B
    __shared__ float s_ic[TILE * 3];   //  6144 B
    __shared__ float s_out[TILE * 3];  //  6144 B  -> 30.7 KB total, 5 blocks/CU by LDS

    const int t = threadIdx.x;
    const int base = blockIdx.x * TILE;
    const int rem = N - base;

    if (rem >= TILE) {
        // ---- fast path: full 512-elem tile, cooperative nt float4 staging ----
        const f4* mc4 = reinterpret_cast<const f4*>(mc + (size_t)base * 9);
        const f4* ic4 = reinterpret_cast<const f4*>(ic + (size_t)base * 3);
        f4* s_mc4 = reinterpret_cast<f4*>(s_mc);
        f4* s_ic4 = reinterpret_cast<f4*>(s_ic);

        // 1152 float4 of mainchain (4.5 per thread), streaming -> nontemporal
        #pragma unroll
        for (int j = 0; j < 4; ++j)
            s_mc4[t + j * BLK] = __builtin_nontemporal_load(&mc4[t + j * BLK]);
        if (t < TILE * 9 / 4 - 4 * BLK)          // remaining 128
            s_mc4[t + 4 * BLK] = __builtin_nontemporal_load(&mc4[t + 4 * BLK]);
        // 384 float4 of inner (1.5 per thread)
        s_ic4[t] = __builtin_nontemporal_load(&ic4[t]);
        if (t < TILE * 3 / 4 - BLK)              // remaining 128
            s_ic4[t + BLK] = __builtin_nontemporal_load(&ic4[t + BLK]);

        __syncthreads();

        #pragma unroll
        for (int e = 0; e < EPT; ++e) {
            const int elem = t + e * BLK;
            float r  = s_ic[elem * 3 + 0];
            float th = s_ic[elem * 3 + 1];
            float ph = s_ic[elem * 3 + 2];

            const float* p = &s_mc[elem * 9];
            float Dx, Dy, Dz;
            nerf_compute(r, th, ph,
                         p[0], p[1], p[2],
                         p[3], p[4], p[5],
                         p[6], p[7], p[8],
                         Dx, Dy, Dz);

            s_out[elem * 3 + 0] = Dx;
            s_out[elem * 3 + 1] = Dy;
            s_out[elem * 3 + 2] = Dz;
        }

        __syncthreads();

        // 384 float4 out, streaming -> nontemporal
        f4* o4 = reinterpret_cast<f4*>(out + (size_t)base * 3);
        const f4* s_out4 = reinterpret_cast<const f4*>(s_out);
        __builtin_nontemporal_store(s_out4[t], &o4[t]);
        if (t < TILE * 3 / 4 - BLK)
            __builtin_nontemporal_store(s_out4[t + BLK], &o4[t + BLK]);
    } else {
        // ---- tail path (last block only) ----
        #pragma unroll
        for (int e = 0; e < EPT; ++e) {
            const int i = base + t + e * BLK;
            if (i < N) {
                const float* p = mc + (size_t)i * 9;
                float r  = ic[(size_t)i * 3 + 0];
                float th = ic[(size_t)i * 3 + 1];
                float ph = ic[(size_t)i * 3 + 2];
                float Dx, Dy, Dz;
                nerf_compute(r, th, ph,
                             p[0], p[1], p[2],
                             p[3], p[4], p[5],
                             p[6], p[7], p[8],
                             Dx, Dy, Dz);
                out[(size_t)i * 3 + 0] = Dx;
                out[(size_t)i * 3 + 1] = Dy;
                out[(size_t)i * 3 + 2] = Dz;
            }
        }
    }
}

extern "C" void kernel_launch(void* const* d_in, const int* in_sizes, int n_in,
                              void* d_out, int out_size, void* d_ws, size_t ws_size,
                              hipStream_t stream) {
    const float* mc = (const float*)d_in[0];   // (3N, 3) float32
    const float* ic = (const float*)d_in[1];   // (N, 3)  float32
    float* out = (float*)d_out;                // (N, 3)  float32

    const int N = in_sizes[1] / 3;
    const int grid = (N + TILE - 1) / TILE;
    nerf_kernel<<<grid, BLK, 0, stream>>>(mc, ic, out, N);
}